// Round 5
// baseline (1693.406 us; speedup 1.0000x reference)
//
#include <hip/hip_runtime.h>
#include <cstdint>

// SelfMatchingLayer: B=32, L=512, H=256, fp32.
// R7: k7 restructured to FIT the 128-VGPR cap instead of fighting it.
//     R6 evidence: launch_bounds(512,2) did NOT raise VGPR_Count (stuck at
//     128); weights went to AGPRs, each use bounced via v_accvgpr_read
//     (~384 extra cy/wave/step -> measured 1875 cy VALU/SIMD/step). New:
//     1024 thr = (u in 0..255) x (ks in 0..3, 64-k quarter); 96 u32 weights
//     + ~25 live temps < 128 VGPRs by construction. 2-stage shfl_xor
//     reduce; GRU redundant on 4 lanes; hs quarter-padded stride-34 u32
//     (unpadded = 4-way bank conflict); 6 accumulator chains for ILP.
//     One barrier/step, hs ping-pong. k1-k6 unchanged.

#define LL 512
#define HH 256

typedef _Float16 half2_t __attribute__((ext_vector_type(2)));

__device__ __forceinline__ float exp2f_fast(float x){
#if defined(__HIP_DEVICE_COMPILE__)
  return __builtin_amdgcn_exp2f(x);
#else
  return exp2f(x);
#endif
}
__device__ __forceinline__ float rcpf_fast(float x){
#if defined(__HIP_DEVICE_COMPILE__)
  return __builtin_amdgcn_rcpf(x);
#else
  return 1.0f/x;
#endif
}
__device__ __forceinline__ float tanh_fast(float x){
  float e = exp2f_fast(x * 2.885390081777927f);   // 2*log2(e)
  return 1.0f - 2.0f * rcpf_fast(1.0f + e);
}
__device__ __forceinline__ float sigmoid_fast(float x){
  return rcpf_fast(1.0f + exp2f_fast(x * -1.4426950408889634f));
}

#define SCALE_K2 2.885390081777927f   // 2*log2(e)

#if defined(__HIP_DEVICE_COMPILE__) && __has_builtin(__builtin_amdgcn_fdot2)
#define USE_FDOT2 1
#endif

__device__ __forceinline__ float dot2_acc(unsigned wb, unsigned hb, float a){
  half2_t wv = __builtin_bit_cast(half2_t, wb);
  half2_t hv = __builtin_bit_cast(half2_t, hb);
#ifdef USE_FDOT2
  return __builtin_amdgcn_fdot2(wv, hv, a, false);
#else
  return a + (float)wv.x*(float)hv.x + (float)wv.y*(float)hv.y;
#endif
}

__device__ __forceinline__ unsigned pack2h(float a, float b){
  half2_t h = { (_Float16)a, (_Float16)b };
  return __builtin_bit_cast(unsigned, h);
}

// ==== fp32 128x128-tile GEMM helpers (k1 only) ===========================
__device__ __forceinline__ void stage_t128(float* Ls, const float* g, int ldg){
  int tid = threadIdx.x;
  int r = tid >> 4, kq = (tid & 15) * 4;
  #pragma unroll
  for (int it = 0; it < 8; it++){
    int rr = r + 16*it;
    float4 v = *(const float4*)(g + (size_t)rr*ldg + kq);
    Ls[(kq+0)*132 + rr] = v.x;
    Ls[(kq+1)*132 + rr] = v.y;
    Ls[(kq+2)*132 + rr] = v.z;
    Ls[(kq+3)*132 + rr] = v.w;
  }
}
__device__ __forceinline__ void rg_inner128(const float* Xs, const float* Ws,
                                            float (&acc)[8][8], int rg, int cg){
  #pragma unroll 2
  for (int k = 0; k < 64; k++){
    const float* xr = Xs + k*132;
    const float* wr = Ws + k*132;
    float4 x0 = *(const float4*)(xr + rg*4);
    float4 x1 = *(const float4*)(xr + 64 + rg*4);
    float4 w0 = *(const float4*)(wr + cg*4);
    float4 w1 = *(const float4*)(wr + 64 + cg*4);
    float xv[8] = {x0.x,x0.y,x0.z,x0.w, x1.x,x1.y,x1.z,x1.w};
    float wv[8] = {w0.x,w0.y,w0.z,w0.w, w1.x,w1.y,w1.z,w1.w};
    #pragma unroll
    for (int i=0;i<8;i++)
      #pragma unroll
      for (int j=0;j<8;j++)
        acc[i][j] = fmaf(xv[i], wv[j], acc[i][j]);
  }
}
#define ROW_OF(i, rg) ((rg)*4 + ((i)&3) + ((i)>>2)*64)
#define COL_OF(j, cg) ((cg)*4 + ((j)&3) + ((j)>>2)*64)

// ==== packed-fp16 128x128-tile GEMM helpers (k4/k5/k6) ===================
__device__ __forceinline__ void stage_t128_h(unsigned* Ls, const float* g, int ldg){
  int tid = threadIdx.x;
  int r = tid >> 4, kq = (tid & 15) * 4;
  #pragma unroll
  for (int it = 0; it < 8; it++){
    int rr = r + 16*it;
    float4 v = *(const float4*)(g + (size_t)rr*ldg + kq);
    Ls[((kq>>1)+0)*132 + rr] = pack2h(v.x, v.y);
    Ls[((kq>>1)+1)*132 + rr] = pack2h(v.z, v.w);
  }
}
__device__ __forceinline__ void stage_dpack_h(unsigned* Ls, const float* g, int ldg){
  int tid = threadIdx.x;
  int kr = tid >> 5, eq = (tid & 31) * 4;
  #pragma unroll
  for (int it = 0; it < 4; it++){
    int lp = kr + 8*it;
    float4 a = *(const float4*)(g + (size_t)(2*lp  )*ldg + eq);
    float4 b = *(const float4*)(g + (size_t)(2*lp+1)*ldg + eq);
    uint4 o;
    o.x = pack2h(a.x, b.x);
    o.y = pack2h(a.y, b.y);
    o.z = pack2h(a.z, b.z);
    o.w = pack2h(a.w, b.w);
    *(uint4*)(Ls + lp*132 + eq) = o;
  }
}
__device__ __forceinline__ void rg_inner128_h(const unsigned* Xs, const unsigned* Ws,
                                              float (&acc)[8][8], int rg, int cg){
  #pragma unroll 2
  for (int kp = 0; kp < 32; kp++){
    const unsigned* xr = Xs + kp*132;
    const unsigned* wr = Ws + kp*132;
    uint4 x0 = *(const uint4*)(xr + rg*4);
    uint4 x1 = *(const uint4*)(xr + 64 + rg*4);
    uint4 w0 = *(const uint4*)(wr + cg*4);
    uint4 w1 = *(const uint4*)(wr + 64 + cg*4);
    unsigned xv[8] = {x0.x,x0.y,x0.z,x0.w, x1.x,x1.y,x1.z,x1.w};
    unsigned wv[8] = {w0.x,w0.y,w0.z,w0.w, w1.x,w1.y,w1.z,w1.w};
    #pragma unroll
    for (int i=0;i<8;i++)
      #pragma unroll
      for (int j=0;j<8;j++)
        acc[i][j] = dot2_acc(xv[i], wv[j], acc[i][j]);
  }
}

// ---------------- K1: HQ' = SC*(P@wq^T+bq) ; PP' = SC*(P@wp^T+bp) --------
__global__ __launch_bounds__(256) void k1_hq_pp(
    const float* __restrict__ P,
    const float* __restrict__ wq_w, const float* __restrict__ wq_b,
    const float* __restrict__ wp_w, const float* __restrict__ wp_b,
    float* __restrict__ HQ, float* __restrict__ PP)
{
  __shared__ __align__(16) float Xs[64*132];
  __shared__ __align__(16) float Ws[64*132];
  int rt = blockIdx.x, ct = blockIdx.y;
  const float* W  = (ct < 2) ? wq_w : wp_w;
  const float* Bv = (ct < 2) ? wq_b : wp_b;
  float* O = (ct < 2) ? HQ : PP;
  int c0 = (ct & 1) * 128, r0 = rt * 128;
  int tid = threadIdx.x, rg = tid & 15, cg = tid >> 4;
  float acc[8][8];
  #pragma unroll
  for (int i=0;i<8;i++)
    #pragma unroll
    for (int j=0;j<8;j++) acc[i][j]=0.f;
  for (int kc = 0; kc < 4; kc++){
    __syncthreads();
    stage_t128(Xs, P + (size_t)r0*HH + kc*64, HH);
    stage_t128(Ws, W + (size_t)c0*HH + kc*64, HH);
    __syncthreads();
    rg_inner128(Xs, Ws, acc, rg, cg);
  }
  float bj[8];
  #pragma unroll
  for (int j=0;j<8;j++) bj[j] = Bv[c0 + COL_OF(j,cg)];
  #pragma unroll
  for (int i=0;i<8;i++){
    int r = r0 + ROW_OF(i,rg);
    #pragma unroll
    for (int j=0;j<8;j++)
      O[(size_t)r*HH + c0 + COL_OF(j,cg)] = SCALE_K2 * (acc[i][j] + bj[j]);
  }
}

// ---------------- K2: S_eff[b,t,l] = -2 * sum_h w_h / (1 + exp2(HQ'+PP')) -
__global__ __launch_bounds__(256) void k2_scores(
    const float* __restrict__ HQ, const float* __restrict__ PP,
    const float* __restrict__ ws_w, float* __restrict__ S)
{
  __shared__ float Hq_c[128*65];
  __shared__ float Pp_c[32*65];
  __shared__ float wsl[256];
  int tid = threadIdx.x;
  int b = blockIdx.y, t0 = blockIdx.x * 32;
  wsl[tid] = ws_w[tid];
  int tg = tid >> 6;
  int lg = tid & 63;
  for (int lc = 0; lc < 4; lc++){
    float acc[8][2];
    #pragma unroll
    for (int i=0;i<8;i++){ acc[i][0]=0.f; acc[i][1]=0.f; }
    for (int hc = 0; hc < 4; hc++){
      __syncthreads();
      {
        int r = tid >> 4, kq = (tid & 15) * 4;
        #pragma unroll
        for (int it=0; it<2; it++){
          int t = r + 16*it;
          float4 v = *(const float4*)(PP + ((size_t)b*LL + t0 + t)*HH + hc*64 + kq);
          float* d = Pp_c + t*65 + kq;
          d[0]=v.x; d[1]=v.y; d[2]=v.z; d[3]=v.w;
        }
      }
      {
        int r = tid >> 4, kq = (tid & 15) * 4;
        #pragma unroll
        for (int it=0; it<8; it++){
          int l = r + 16*it;
          float4 v = *(const float4*)(HQ + ((size_t)b*LL + lc*128 + l)*HH + hc*64 + kq);
          float* d = Hq_c + l*65 + kq;
          d[0]=v.x; d[1]=v.y; d[2]=v.z; d[3]=v.w;
        }
      }
      __syncthreads();
      #pragma unroll 2
      for (int h = 0; h < 64; h++){
        float w = wsl[hc*64 + h];
        float pp[8], hq[2];
        #pragma unroll
        for (int i=0;i<8;i++) pp[i] = Pp_c[(tg + 4*i)*65 + h];
        #pragma unroll
        for (int j=0;j<2;j++) hq[j] = Hq_c[(2*lg + j)*65 + h];
        #pragma unroll
        for (int i=0;i<8;i++)
          #pragma unroll
          for (int j=0;j<2;j++){
            float e = exp2f_fast(pp[i] + hq[j]);
            acc[i][j] = fmaf(w, rcpf_fast(1.0f + e), acc[i][j]);
          }
      }
    }
    #pragma unroll
    for (int i=0;i<8;i++)
      #pragma unroll
      for (int j=0;j<2;j++)
        S[((size_t)b*LL + t0 + tg + 4*i)*LL + lc*128 + 2*lg + j] = -2.0f*acc[i][j];
    __syncthreads();
  }
}

// ---------------- K3: softmax over l, in place; one wave per row ----------
__global__ __launch_bounds__(256) void k3_softmax(float* __restrict__ S)
{
  int wave = threadIdx.x >> 6, lane = threadIdx.x & 63;
  size_t row = (size_t)blockIdx.x*4 + wave;
  float* p = S + row*LL;
  float v[8];
  #pragma unroll
  for (int i=0;i<8;i++) v[i] = p[lane + 64*i];
  float m = v[0];
  #pragma unroll
  for (int i=1;i<8;i++) m = fmaxf(m, v[i]);
  #pragma unroll
  for (int off=32; off>=1; off>>=1) m = fmaxf(m, __shfl_xor(m, off, 64));
  float s = 0.f;
  #pragma unroll
  for (int i=0;i<8;i++){ v[i] = exp2f_fast((v[i]-m)*1.4426950408889634f); s += v[i]; }
  #pragma unroll
  for (int off=32; off>=1; off>>=1) s += __shfl_xor(s, off, 64);
  float inv = 1.0f / s;
  #pragma unroll
  for (int i=0;i<8;i++) p[lane + 64*i] = v[i]*inv;
}

// ---------------- K4: C[b,t,:] = attn[b,t,:] @ P[b,:,:] (fdot2) -----------
__global__ __launch_bounds__(256, 4) void k4_context(
    const float* __restrict__ S, const float* __restrict__ P, float* __restrict__ C)
{
  __shared__ __align__(16) unsigned As[32*132];
  __shared__ __align__(16) unsigned Ps[32*132];
  int j0 = blockIdx.x * 128, t0 = blockIdx.y * 128, b = blockIdx.z;
  int tid = threadIdx.x, rg = tid & 15, cg = tid >> 4;
  float acc[8][8];
  #pragma unroll
  for (int i=0;i<8;i++)
    #pragma unroll
    for (int j=0;j<8;j++) acc[i][j]=0.f;
  for (int lc = 0; lc < 8; lc++){
    int l0 = lc*64;
    __syncthreads();
    stage_t128_h (As, S + ((size_t)b*LL + t0)*LL + l0, LL);
    stage_dpack_h(Ps, P + ((size_t)b*LL + l0)*HH + j0, HH);
    __syncthreads();
    rg_inner128_h(As, Ps, acc, rg, cg);
  }
  #pragma unroll
  for (int i=0;i<8;i++){
    int t = t0 + ROW_OF(i,rg);
    #pragma unroll
    for (int j=0;j<8;j++)
      C[((size_t)b*LL + t)*HH + j0 + COL_OF(j,cg)] = acc[i][j];
  }
}

// ---------------- K5: Cg = sigmoid([P|C]@wg^T + bg) * C (fdot2) -----------
__global__ __launch_bounds__(256, 4) void k5_gate(
    const float* __restrict__ P, const float* __restrict__ C,
    const float* __restrict__ wg_w, const float* __restrict__ wg_b,
    float* __restrict__ CG)
{
  __shared__ __align__(16) unsigned Xs[32*132];
  __shared__ __align__(16) unsigned Ws[32*132];
  int r0 = blockIdx.x*128, c0 = blockIdx.y*128;
  int tid = threadIdx.x, rg = tid & 15, cg = tid >> 4;
  float acc[8][8];
  #pragma unroll
  for (int i=0;i<8;i++)
    #pragma unroll
    for (int j=0;j<8;j++) acc[i][j]=0.f;
  for (int kc = 0; kc < 8; kc++){
    const float* Xsrc = (kc < 4) ? (P + (size_t)r0*HH + kc*64)
                                 : (C + (size_t)r0*HH + (kc-4)*64);
    __syncthreads();
    stage_t128_h(Xs, Xsrc, HH);
    stage_t128_h(Ws, wg_w + (size_t)c0*(2*HH) + kc*64, 2*HH);
    __syncthreads();
    rg_inner128_h(Xs, Ws, acc, rg, cg);
  }
  float bj[8];
  #pragma unroll
  for (int j=0;j<8;j++) bj[j] = wg_b[c0 + COL_OF(j,cg)];
  #pragma unroll
  for (int i=0;i<8;i++){
    int r = r0 + ROW_OF(i,rg);
    #pragma unroll
    for (int j=0;j<8;j++){
      int c = c0 + COL_OF(j,cg);
      float g = sigmoid_fast(acc[i][j] + bj[j]);
      CG[(size_t)r*HH + c] = g * C[(size_t)r*HH + c];
    }
  }
}

// ---------------- K6: GI_{l,r} = Cg @ Wih^T + bih (fdot2) -----------------
__global__ __launch_bounds__(256, 4) void k6_gi(
    const float* __restrict__ CG,
    const float* __restrict__ Wih_l, const float* __restrict__ bih_l,
    const float* __restrict__ Wih_r, const float* __restrict__ bih_r,
    float* __restrict__ GIL, float* __restrict__ GIR)
{
  __shared__ __align__(16) unsigned Xs[32*132];
  __shared__ __align__(16) unsigned Ws[32*132];
  int rt = blockIdx.x, ct = blockIdx.y;
  int dir = (ct >= 6);
  const float* Wih = dir ? Wih_r : Wih_l;
  const float* bih = dir ? bih_r : bih_l;
  float* GI = dir ? GIR : GIL;
  int c0 = (ct % 6) * 128, r0 = rt * 128;
  int tid = threadIdx.x, rg = tid & 15, cg = tid >> 4;
  float acc[8][8];
  #pragma unroll
  for (int i=0;i<8;i++)
    #pragma unroll
    for (int j=0;j<8;j++) acc[i][j]=0.f;
  for (int kc = 0; kc < 4; kc++){
    __syncthreads();
    stage_t128_h(Xs, CG + (size_t)r0*HH + kc*64, HH);
    stage_t128_h(Ws, Wih + (size_t)c0*HH + kc*64, HH);
    __syncthreads();
    rg_inner128_h(Xs, Ws, acc, rg, cg);
  }
  float bj[8];
  #pragma unroll
  for (int j=0;j<8;j++) bj[j] = bih[c0 + COL_OF(j,cg)];
  #pragma unroll
  for (int i=0;i<8;i++){
    int r = r0 + ROW_OF(i,rg);
    #pragma unroll
    for (int j=0;j<8;j++)
      GI[(size_t)r*768 + c0 + COL_OF(j,cg)] = acc[i][j] + bj[j];
  }
}

// ---------------- K7: GRU scans (R7) --------------------------------------
// 64 blocks (b,dir) x 1024 threads. Thread t: u = t>>2 (output dim),
// ks = t&3 (64-k quarter). Gate rows {u,u+256,u+512} over the quarter:
// 96 u32 fp16-pair weights + ~25 temps < 128-VGPR cap BY CONSTRUCTION
// (R5/R6 lesson: 192 u32 never fit; AGPR bounce ate ~384cy/wave/step).
// 2-stage shfl_xor reduce; GRU inline redundant on 4 lanes; hs ping-pong
// quarter-padded (stride 34 u32: unpadded quarters land on one bank pair,
// 4-way conflict). One barrier per step.
__global__ __launch_bounds__(1024, 4) void k7_scan(
    const float* __restrict__ GIL, const float* __restrict__ GIR,
    const float* __restrict__ Whh_l, const float* __restrict__ bhh_l,
    const float* __restrict__ Whh_r, const float* __restrict__ bhh_r,
    float* __restrict__ out)
{
  int b   = blockIdx.x >> 1;
  int dir = blockIdx.x & 1;
  int t   = threadIdx.x;
  int u   = t >> 2;          // output dim 0..255
  int ks  = t & 3;           // k quarter
  int k0  = ks * 64;
  const float* GI  = dir ? GIR : GIL;
  const float* Whh = dir ? Whh_r : Whh_l;
  const float* bhh = dir ? bhh_r : bhh_l;

  // Weights for rows u, u+256, u+512 over k0..k0+63: 32 u32 each.
  unsigned w_r[32], w_z[32], w_n[32];
  {
    const float2* wr = (const float2*)(Whh + (size_t)(u      )*HH + k0);
    const float2* wz = (const float2*)(Whh + (size_t)(u + 256)*HH + k0);
    const float2* wn = (const float2*)(Whh + (size_t)(u + 512)*HH + k0);
    #pragma unroll
    for (int p = 0; p < 32; p++){
      float2 a = wr[p]; w_r[p] = pack2h(a.x, a.y);
      float2 c = wz[p]; w_z[p] = pack2h(c.x, c.y);
      float2 d = wn[p]; w_n[p] = pack2h(d.x, d.y);
    }
  }
  float b_r = bhh[u], b_z = bhh[u + 256], b_n = bhh[u + 512];

  // fp16 h ping-pong; quarter q at u32 offset q*34 (34 even: b64-aligned,
  // banks 2c+2q distinct -> conflict-free).
  __shared__ __align__(16) unsigned hsbuf[2][136];
  __shared__ __align__(16) float gi_buf[32*768];     // 96 KB
  __shared__ __align__(16) float out_buf[32*256];    // 32 KB
  if (t < 136){ hsbuf[0][t] = 0; }

  float hprev = 0.f;

  #pragma unroll 1
  for (int chunk = 0; chunk < 16; chunk++){
    int s0 = chunk * 32;
    int tlo = dir ? (LL - s0 - 32) : s0;    // staged t range [tlo, tlo+31]
    // stage 32 steps of gi: 6144 float4 over 1024 threads
    {
      const float4* src = (const float4*)(GI + ((size_t)b*LL + tlo)*768);
      float4* dst = (float4*)gi_buf;
      #pragma unroll
      for (int i = 0; i < 6; i++)
        dst[t + 1024*i] = src[t + 1024*i];
    }
    __syncthreads();   // gi_buf ready; hs writes from prev step visible

    #pragma unroll 1
    for (int p = 0; p < 32; p++){
      int s = s0 + p;
      int tt = dir ? (LL-1-s) : s;
      int gidx = tt - tlo;                  // 0..31
      const unsigned* hq = hsbuf[s & 1] + ks*34;
      float ar0=0.f, ar1=0.f, az0=0.f, az1=0.f, an0=0.f, an1=0.f;
      #pragma unroll
      for (int c = 0; c < 16; c += 2){
        uint2 q0 = ((const uint2*)hq)[c];
        uint2 q1 = ((const uint2*)hq)[c+1];
        ar0 = dot2_acc(w_r[c*2  ], q0.x, ar0);
        az0 = dot2_acc(w_z[c*2  ], q0.x, az0);
        an0 = dot2_acc(w_n[c*2  ], q0.x, an0);
        ar1 = dot2_acc(w_r[c*2+1], q0.y, ar1);
        az1 = dot2_acc(w_z[c*2+1], q0.y, az1);
        an1 = dot2_acc(w_n[c*2+1], q0.y, an1);
        ar0 = dot2_acc(w_r[c*2+2], q1.x, ar0);
        az0 = dot2_acc(w_z[c*2+2], q1.x, az0);
        an0 = dot2_acc(w_n[c*2+2], q1.x, an0);
        ar1 = dot2_acc(w_r[c*2+3], q1.y, ar1);
        az1 = dot2_acc(w_z[c*2+3], q1.y, az1);
        an1 = dot2_acc(w_n[c*2+3], q1.y, an1);
      }
      float ar = ar0 + ar1, az = az0 + az1, an = an0 + an1;
      // combine 4 k-quarters: xor-1 then xor-2; all lanes get full sums
      ar += __shfl_xor(ar, 1, 64);
      az += __shfl_xor(az, 1, 64);
      an += __shfl_xor(an, 1, 64);
      ar += __shfl_xor(ar, 2, 64);
      az += __shfl_xor(az, 2, 64);
      an += __shfl_xor(an, 2, 64);
      const float* g = gi_buf + (size_t)gidx*768;
      float r  = sigmoid_fast(g[u      ] + ar + b_r);
      float z  = sigmoid_fast(g[u + 256] + az + b_z);
      float n  = tanh_fast  (g[u + 512] + r*(an + b_n));
      float hn = z*(hprev - n) + n;
      hprev = hn;
      if (ks == 0){
        out_buf[p*256 + u] = hn;
        ((unsigned short*)hsbuf[(s & 1) ^ 1])[(u >> 6)*68 + (u & 63)] =
            __builtin_bit_cast(unsigned short, (_Float16)hn);
      }
      __syncthreads();   // hs(write-buf) ready; separates reads from next writes
    }
    // flush outputs for this chunk (coalesced 256-wide per step)
    for (int i = t; i < 32*256; i += 1024){
      int p = i >> 8, uu = i & 255;
      int s = s0 + p;
      int tt = dir ? (LL-1-s) : s;
      out[((size_t)b*LL + tt)*(2*HH) + dir*HH + uu] = out_buf[i];
    }
    __syncthreads();   // out_buf/gi_buf safe to reuse
  }
}

extern "C" void kernel_launch(void* const* d_in, const int* in_sizes, int n_in,
                              void* d_out, int out_size, void* d_ws, size_t ws_size,
                              hipStream_t stream)
{
  const float* P    = (const float*)d_in[0];
  const float* wq_w = (const float*)d_in[1];
  const float* wq_b = (const float*)d_in[2];
  const float* wp_w = (const float*)d_in[3];
  const float* wp_b = (const float*)d_in[4];
  const float* ws_w = (const float*)d_in[5];
  // d_in[6] = ws_b: softmax-invariant, unused
  const float* wg_w = (const float*)d_in[7];
  const float* wg_b = (const float*)d_in[8];
  const float* Wih_l= (const float*)d_in[9];
  const float* Whh_l= (const float*)d_in[10];
  const float* bih_l= (const float*)d_in[11];
  const float* bhh_l= (const float*)d_in[12];
  const float* Wih_r= (const float*)d_in[13];
  const float* Whh_r= (const float*)d_in[14];
  const float* bih_r= (const float*)d_in[15];
  const float* bhh_r= (const float*)d_in[16];

  float* ws  = (float*)d_ws;
  float* HQ  = ws;                    //  4,194,304
  float* PP  = ws + 4194304;          //  4,194,304
  float* S   = ws + 8388608;          //  8,388,608
  float* C   = ws + 16777216;         //  4,194,304
  float* CG  = ws + 20971520;         //  4,194,304
  float* GIR = ws + 25165824;         // 12,582,912
  float* GIL = ws;                    // 12,582,912 (aliases HQ/PP/S-front; dead by k6)
  float* out = (float*)d_out;

  k1_hq_pp  <<<dim3(128, 4),    256, 0, stream>>>(P, wq_w, wq_b, wp_w, wp_b, HQ, PP);
  k2_scores <<<dim3(16, 32),    256, 0, stream>>>(HQ, PP, ws_w, S);
  k3_softmax<<<4096,            256, 0, stream>>>(S);
  k4_context<<<dim3(2, 4, 32),  256, 0, stream>>>(S, P, C);
  k5_gate   <<<dim3(128, 2),    256, 0, stream>>>(P, C, wg_w, wg_b, CG);
  k6_gi     <<<dim3(128, 12),   256, 0, stream>>>(CG, Wih_l, bih_l, Wih_r, bih_r, GIL, GIR);
  k7_scan   <<<64,             1024, 0, stream>>>(GIL, GIR, Whh_l, bhh_l, Whh_r, bhh_r, out);
}

// Round 7
// 1485.922 us; speedup vs baseline: 1.1396x; 1.1396x over previous
//
#include <hip/hip_runtime.h>
#include <cstdint>

// SelfMatchingLayer: B=32, L=512, H=256, fp32.
// R8 (resubmit; broker timeout, never ran): k7 = R6 structure (512 thr =
//     (u, ks in 0..1), 192-u32 weights, launch_bounds(512,2), one
//     barrier/step -- measured 657us best) + REGISTER-PRESSURE PACING.
//     R6 spilled not because of the weights but because of peak pressure:
//     12 in-flight float4 staging (48 regs) + 16 hoisted h-words (64 regs)
//     on top of 192 weights = ~290 > 256 budget. R8 paces: staging 3
//     rounds x 4 float4; h-reads 4 sub-chunks x 4 uint4; weight preload
//     8 rounds x (3x8 float2) with sched_barrier(0) fences.
//     Peak ~239 <= 256 -> no scratch by construction. R7 (96w @ 16 waves,
//     849us, VGPR=64) abandoned: weights = 75% of the whole CU file there.

#define LL 512
#define HH 256

typedef _Float16 half2_t __attribute__((ext_vector_type(2)));

__device__ __forceinline__ float exp2f_fast(float x){
#if defined(__HIP_DEVICE_COMPILE__)
  return __builtin_amdgcn_exp2f(x);
#else
  return exp2f(x);
#endif
}
__device__ __forceinline__ float rcpf_fast(float x){
#if defined(__HIP_DEVICE_COMPILE__)
  return __builtin_amdgcn_rcpf(x);
#else
  return 1.0f/x;
#endif
}
__device__ __forceinline__ float tanh_fast(float x){
  float e = exp2f_fast(x * 2.885390081777927f);   // 2*log2(e)
  return 1.0f - 2.0f * rcpf_fast(1.0f + e);
}
__device__ __forceinline__ float sigmoid_fast(float x){
  return rcpf_fast(1.0f + exp2f_fast(x * -1.4426950408889634f));
}

#define SCALE_K2 2.885390081777927f   // 2*log2(e)

#if defined(__HIP_DEVICE_COMPILE__) && __has_builtin(__builtin_amdgcn_fdot2)
#define USE_FDOT2 1
#endif

__device__ __forceinline__ float dot2_acc(unsigned wb, unsigned hb, float a){
  half2_t wv = __builtin_bit_cast(half2_t, wb);
  half2_t hv = __builtin_bit_cast(half2_t, hb);
#ifdef USE_FDOT2
  return __builtin_amdgcn_fdot2(wv, hv, a, false);
#else
  return a + (float)wv.x*(float)hv.x + (float)wv.y*(float)hv.y;
#endif
}

__device__ __forceinline__ unsigned pack2h(float a, float b){
  half2_t h = { (_Float16)a, (_Float16)b };
  return __builtin_bit_cast(unsigned, h);
}

// ==== fp32 128x128-tile GEMM helpers (k1 only) ===========================
__device__ __forceinline__ void stage_t128(float* Ls, const float* g, int ldg){
  int tid = threadIdx.x;
  int r = tid >> 4, kq = (tid & 15) * 4;
  #pragma unroll
  for (int it = 0; it < 8; it++){
    int rr = r + 16*it;
    float4 v = *(const float4*)(g + (size_t)rr*ldg + kq);
    Ls[(kq+0)*132 + rr] = v.x;
    Ls[(kq+1)*132 + rr] = v.y;
    Ls[(kq+2)*132 + rr] = v.z;
    Ls[(kq+3)*132 + rr] = v.w;
  }
}
__device__ __forceinline__ void rg_inner128(const float* Xs, const float* Ws,
                                            float (&acc)[8][8], int rg, int cg){
  #pragma unroll 2
  for (int k = 0; k < 64; k++){
    const float* xr = Xs + k*132;
    const float* wr = Ws + k*132;
    float4 x0 = *(const float4*)(xr + rg*4);
    float4 x1 = *(const float4*)(xr + 64 + rg*4);
    float4 w0 = *(const float4*)(wr + cg*4);
    float4 w1 = *(const float4*)(wr + 64 + cg*4);
    float xv[8] = {x0.x,x0.y,x0.z,x0.w, x1.x,x1.y,x1.z,x1.w};
    float wv[8] = {w0.x,w0.y,w0.z,w0.w, w1.x,w1.y,w1.z,w1.w};
    #pragma unroll
    for (int i=0;i<8;i++)
      #pragma unroll
      for (int j=0;j<8;j++)
        acc[i][j] = fmaf(xv[i], wv[j], acc[i][j]);
  }
}
#define ROW_OF(i, rg) ((rg)*4 + ((i)&3) + ((i)>>2)*64)
#define COL_OF(j, cg) ((cg)*4 + ((j)&3) + ((j)>>2)*64)

// ==== packed-fp16 128x128-tile GEMM helpers (k4/k5/k6) ===================
__device__ __forceinline__ void stage_t128_h(unsigned* Ls, const float* g, int ldg){
  int tid = threadIdx.x;
  int r = tid >> 4, kq = (tid & 15) * 4;
  #pragma unroll
  for (int it = 0; it < 8; it++){
    int rr = r + 16*it;
    float4 v = *(const float4*)(g + (size_t)rr*ldg + kq);
    Ls[((kq>>1)+0)*132 + rr] = pack2h(v.x, v.y);
    Ls[((kq>>1)+1)*132 + rr] = pack2h(v.z, v.w);
  }
}
__device__ __forceinline__ void stage_dpack_h(unsigned* Ls, const float* g, int ldg){
  int tid = threadIdx.x;
  int kr = tid >> 5, eq = (tid & 31) * 4;
  #pragma unroll
  for (int it = 0; it < 4; it++){
    int lp = kr + 8*it;
    float4 a = *(const float4*)(g + (size_t)(2*lp  )*ldg + eq);
    float4 b = *(const float4*)(g + (size_t)(2*lp+1)*ldg + eq);
    uint4 o;
    o.x = pack2h(a.x, b.x);
    o.y = pack2h(a.y, b.y);
    o.z = pack2h(a.z, b.z);
    o.w = pack2h(a.w, b.w);
    *(uint4*)(Ls + lp*132 + eq) = o;
  }
}
__device__ __forceinline__ void rg_inner128_h(const unsigned* Xs, const unsigned* Ws,
                                              float (&acc)[8][8], int rg, int cg){
  #pragma unroll 2
  for (int kp = 0; kp < 32; kp++){
    const unsigned* xr = Xs + kp*132;
    const unsigned* wr = Ws + kp*132;
    uint4 x0 = *(const uint4*)(xr + rg*4);
    uint4 x1 = *(const uint4*)(xr + 64 + rg*4);
    uint4 w0 = *(const uint4*)(wr + cg*4);
    uint4 w1 = *(const uint4*)(wr + 64 + cg*4);
    unsigned xv[8] = {x0.x,x0.y,x0.z,x0.w, x1.x,x1.y,x1.z,x1.w};
    unsigned wv[8] = {w0.x,w0.y,w0.z,w0.w, w1.x,w1.y,w1.z,w1.w};
    #pragma unroll
    for (int i=0;i<8;i++)
      #pragma unroll
      for (int j=0;j<8;j++)
        acc[i][j] = dot2_acc(xv[i], wv[j], acc[i][j]);
  }
}

// ---------------- K1: HQ' = SC*(P@wq^T+bq) ; PP' = SC*(P@wp^T+bp) --------
__global__ __launch_bounds__(256) void k1_hq_pp(
    const float* __restrict__ P,
    const float* __restrict__ wq_w, const float* __restrict__ wq_b,
    const float* __restrict__ wp_w, const float* __restrict__ wp_b,
    float* __restrict__ HQ, float* __restrict__ PP)
{
  __shared__ __align__(16) float Xs[64*132];
  __shared__ __align__(16) float Ws[64*132];
  int rt = blockIdx.x, ct = blockIdx.y;
  const float* W  = (ct < 2) ? wq_w : wp_w;
  const float* Bv = (ct < 2) ? wq_b : wp_b;
  float* O = (ct < 2) ? HQ : PP;
  int c0 = (ct & 1) * 128, r0 = rt * 128;
  int tid = threadIdx.x, rg = tid & 15, cg = tid >> 4;
  float acc[8][8];
  #pragma unroll
  for (int i=0;i<8;i++)
    #pragma unroll
    for (int j=0;j<8;j++) acc[i][j]=0.f;
  for (int kc = 0; kc < 4; kc++){
    __syncthreads();
    stage_t128(Xs, P + (size_t)r0*HH + kc*64, HH);
    stage_t128(Ws, W + (size_t)c0*HH + kc*64, HH);
    __syncthreads();
    rg_inner128(Xs, Ws, acc, rg, cg);
  }
  float bj[8];
  #pragma unroll
  for (int j=0;j<8;j++) bj[j] = Bv[c0 + COL_OF(j,cg)];
  #pragma unroll
  for (int i=0;i<8;i++){
    int r = r0 + ROW_OF(i,rg);
    #pragma unroll
    for (int j=0;j<8;j++)
      O[(size_t)r*HH + c0 + COL_OF(j,cg)] = SCALE_K2 * (acc[i][j] + bj[j]);
  }
}

// ---------------- K2: S_eff[b,t,l] = -2 * sum_h w_h / (1 + exp2(HQ'+PP')) -
__global__ __launch_bounds__(256) void k2_scores(
    const float* __restrict__ HQ, const float* __restrict__ PP,
    const float* __restrict__ ws_w, float* __restrict__ S)
{
  __shared__ float Hq_c[128*65];
  __shared__ float Pp_c[32*65];
  __shared__ float wsl[256];
  int tid = threadIdx.x;
  int b = blockIdx.y, t0 = blockIdx.x * 32;
  wsl[tid] = ws_w[tid];
  int tg = tid >> 6;
  int lg = tid & 63;
  for (int lc = 0; lc < 4; lc++){
    float acc[8][2];
    #pragma unroll
    for (int i=0;i<8;i++){ acc[i][0]=0.f; acc[i][1]=0.f; }
    for (int hc = 0; hc < 4; hc++){
      __syncthreads();
      {
        int r = tid >> 4, kq = (tid & 15) * 4;
        #pragma unroll
        for (int it=0; it<2; it++){
          int t = r + 16*it;
          float4 v = *(const float4*)(PP + ((size_t)b*LL + t0 + t)*HH + hc*64 + kq);
          float* d = Pp_c + t*65 + kq;
          d[0]=v.x; d[1]=v.y; d[2]=v.z; d[3]=v.w;
        }
      }
      {
        int r = tid >> 4, kq = (tid & 15) * 4;
        #pragma unroll
        for (int it=0; it<8; it++){
          int l = r + 16*it;
          float4 v = *(const float4*)(HQ + ((size_t)b*LL + lc*128 + l)*HH + hc*64 + kq);
          float* d = Hq_c + l*65 + kq;
          d[0]=v.x; d[1]=v.y; d[2]=v.z; d[3]=v.w;
        }
      }
      __syncthreads();
      #pragma unroll 2
      for (int h = 0; h < 64; h++){
        float w = wsl[hc*64 + h];
        float pp[8], hq[2];
        #pragma unroll
        for (int i=0;i<8;i++) pp[i] = Pp_c[(tg + 4*i)*65 + h];
        #pragma unroll
        for (int j=0;j<2;j++) hq[j] = Hq_c[(2*lg + j)*65 + h];
        #pragma unroll
        for (int i=0;i<8;i++)
          #pragma unroll
          for (int j=0;j<2;j++){
            float e = exp2f_fast(pp[i] + hq[j]);
            acc[i][j] = fmaf(w, rcpf_fast(1.0f + e), acc[i][j]);
          }
      }
    }
    #pragma unroll
    for (int i=0;i<8;i++)
      #pragma unroll
      for (int j=0;j<2;j++)
        S[((size_t)b*LL + t0 + tg + 4*i)*LL + lc*128 + 2*lg + j] = -2.0f*acc[i][j];
    __syncthreads();
  }
}

// ---------------- K3: softmax over l, in place; one wave per row ----------
__global__ __launch_bounds__(256) void k3_softmax(float* __restrict__ S)
{
  int wave = threadIdx.x >> 6, lane = threadIdx.x & 63;
  size_t row = (size_t)blockIdx.x*4 + wave;
  float* p = S + row*LL;
  float v[8];
  #pragma unroll
  for (int i=0;i<8;i++) v[i] = p[lane + 64*i];
  float m = v[0];
  #pragma unroll
  for (int i=1;i<8;i++) m = fmaxf(m, v[i]);
  #pragma unroll
  for (int off=32; off>=1; off>>=1) m = fmaxf(m, __shfl_xor(m, off, 64));
  float s = 0.f;
  #pragma unroll
  for (int i=0;i<8;i++){ v[i] = exp2f_fast((v[i]-m)*1.4426950408889634f); s += v[i]; }
  #pragma unroll
  for (int off=32; off>=1; off>>=1) s += __shfl_xor(s, off, 64);
  float inv = 1.0f / s;
  #pragma unroll
  for (int i=0;i<8;i++) p[lane + 64*i] = v[i]*inv;
}

// ---------------- K4: C[b,t,:] = attn[b,t,:] @ P[b,:,:] (fdot2) -----------
__global__ __launch_bounds__(256, 4) void k4_context(
    const float* __restrict__ S, const float* __restrict__ P, float* __restrict__ C)
{
  __shared__ __align__(16) unsigned As[32*132];
  __shared__ __align__(16) unsigned Ps[32*132];
  int j0 = blockIdx.x * 128, t0 = blockIdx.y * 128, b = blockIdx.z;
  int tid = threadIdx.x, rg = tid & 15, cg = tid >> 4;
  float acc[8][8];
  #pragma unroll
  for (int i=0;i<8;i++)
    #pragma unroll
    for (int j=0;j<8;j++) acc[i][j]=0.f;
  for (int lc = 0; lc < 8; lc++){
    int l0 = lc*64;
    __syncthreads();
    stage_t128_h (As, S + ((size_t)b*LL + t0)*LL + l0, LL);
    stage_dpack_h(Ps, P + ((size_t)b*LL + l0)*HH + j0, HH);
    __syncthreads();
    rg_inner128_h(As, Ps, acc, rg, cg);
  }
  #pragma unroll
  for (int i=0;i<8;i++){
    int t = t0 + ROW_OF(i,rg);
    #pragma unroll
    for (int j=0;j<8;j++)
      C[((size_t)b*LL + t)*HH + j0 + COL_OF(j,cg)] = acc[i][j];
  }
}

// ---------------- K5: Cg = sigmoid([P|C]@wg^T + bg) * C (fdot2) -----------
__global__ __launch_bounds__(256, 4) void k5_gate(
    const float* __restrict__ P, const float* __restrict__ C,
    const float* __restrict__ wg_w, const float* __restrict__ wg_b,
    float* __restrict__ CG)
{
  __shared__ __align__(16) unsigned Xs[32*132];
  __shared__ __align__(16) unsigned Ws[32*132];
  int r0 = blockIdx.x*128, c0 = blockIdx.y*128;
  int tid = threadIdx.x, rg = tid & 15, cg = tid >> 4;
  float acc[8][8];
  #pragma unroll
  for (int i=0;i<8;i++)
    #pragma unroll
    for (int j=0;j<8;j++) acc[i][j]=0.f;
  for (int kc = 0; kc < 8; kc++){
    const float* Xsrc = (kc < 4) ? (P + (size_t)r0*HH + kc*64)
                                 : (C + (size_t)r0*HH + (kc-4)*64);
    __syncthreads();
    stage_t128_h(Xs, Xsrc, HH);
    stage_t128_h(Ws, wg_w + (size_t)c0*(2*HH) + kc*64, 2*HH);
    __syncthreads();
    rg_inner128_h(Xs, Ws, acc, rg, cg);
  }
  float bj[8];
  #pragma unroll
  for (int j=0;j<8;j++) bj[j] = wg_b[c0 + COL_OF(j,cg)];
  #pragma unroll
  for (int i=0;i<8;i++){
    int r = r0 + ROW_OF(i,rg);
    #pragma unroll
    for (int j=0;j<8;j++){
      int c = c0 + COL_OF(j,cg);
      float g = sigmoid_fast(acc[i][j] + bj[j]);
      CG[(size_t)r*HH + c] = g * C[(size_t)r*HH + c];
    }
  }
}

// ---------------- K6: GI_{l,r} = Cg @ Wih^T + bih (fdot2) -----------------
__global__ __launch_bounds__(256, 4) void k6_gi(
    const float* __restrict__ CG,
    const float* __restrict__ Wih_l, const float* __restrict__ bih_l,
    const float* __restrict__ Wih_r, const float* __restrict__ bih_r,
    float* __restrict__ GIL, float* __restrict__ GIR)
{
  __shared__ __align__(16) unsigned Xs[32*132];
  __shared__ __align__(16) unsigned Ws[32*132];
  int rt = blockIdx.x, ct = blockIdx.y;
  int dir = (ct >= 6);
  const float* Wih = dir ? Wih_r : Wih_l;
  const float* bih = dir ? bih_r : bih_l;
  float* GI = dir ? GIR : GIL;
  int c0 = (ct % 6) * 128, r0 = rt * 128;
  int tid = threadIdx.x, rg = tid & 15, cg = tid >> 4;
  float acc[8][8];
  #pragma unroll
  for (int i=0;i<8;i++)
    #pragma unroll
    for (int j=0;j<8;j++) acc[i][j]=0.f;
  for (int kc = 0; kc < 4; kc++){
    __syncthreads();
    stage_t128_h(Xs, CG + (size_t)r0*HH + kc*64, HH);
    stage_t128_h(Ws, Wih + (size_t)c0*HH + kc*64, HH);
    __syncthreads();
    rg_inner128_h(Xs, Ws, acc, rg, cg);
  }
  float bj[8];
  #pragma unroll
  for (int j=0;j<8;j++) bj[j] = bih[c0 + COL_OF(j,cg)];
  #pragma unroll
  for (int i=0;i<8;i++){
    int r = r0 + ROW_OF(i,rg);
    #pragma unroll
    for (int j=0;j<8;j++)
      GI[(size_t)r*768 + c0 + COL_OF(j,cg)] = acc[i][j] + bj[j];
  }
}

// ---------------- K7: GRU scans (R8 = R6 + pacing) ------------------------
// 64 blocks (b,dir) x 512 threads. Thread t: u = t>>1, ks = t&1 (k half).
// Gate rows {u,u+256,u+512} over k in [ks*128, +128): 64 u32 weights/gate,
// 192 total. Pacing keeps PEAK pressure <= ~239 < 256 (the 2-waves/EU
// budget): staging 3 rounds x 4 float4; h-reads 4 sub-chunks x 4 uint4;
// weight preload 8 rounds x (3x8 float2). sched_barrier(0) = compile-time
// fence only.
__global__ __launch_bounds__(512, 2) void k7_scan(
    const float* __restrict__ GIL, const float* __restrict__ GIR,
    const float* __restrict__ Whh_l, const float* __restrict__ bhh_l,
    const float* __restrict__ Whh_r, const float* __restrict__ bhh_r,
    float* __restrict__ out)
{
  int b   = blockIdx.x >> 1;
  int dir = blockIdx.x & 1;
  int t   = threadIdx.x;
  int u   = t >> 1;          // output dim 0..255
  int ks  = t & 1;           // k half
  int k0  = ks * 128;
  const float* GI  = dir ? GIR : GIL;
  const float* Whh = dir ? Whh_r : Whh_l;
  const float* bhh = dir ? bhh_r : bhh_l;

  // Weights for rows u, u+256, u+512 over k0..k0+127: 64 u32 each.
  // Paced preload: 8 float2 in flight per round per gate.
  unsigned w_r[64], w_z[64], w_n[64];
  {
    const float2* wr = (const float2*)(Whh + (size_t)(u      )*HH + k0);
    const float2* wz = (const float2*)(Whh + (size_t)(u + 256)*HH + k0);
    const float2* wn = (const float2*)(Whh + (size_t)(u + 512)*HH + k0);
    #pragma unroll
    for (int pc = 0; pc < 8; pc++){
      #pragma unroll
      for (int p = pc*8; p < pc*8+8; p++){ float2 a = wr[p]; w_r[p] = pack2h(a.x, a.y); }
      __builtin_amdgcn_sched_barrier(0);
      #pragma unroll
      for (int p = pc*8; p < pc*8+8; p++){ float2 a = wz[p]; w_z[p] = pack2h(a.x, a.y); }
      __builtin_amdgcn_sched_barrier(0);
      #pragma unroll
      for (int p = pc*8; p < pc*8+8; p++){ float2 a = wn[p]; w_n[p] = pack2h(a.x, a.y); }
      __builtin_amdgcn_sched_barrier(0);
    }
  }
  float b_r = bhh[u], b_z = bhh[u + 256], b_n = bhh[u + 512];

  __shared__ __align__(16) unsigned hsbuf[2][128];   // fp16 h, ping-pong
  __shared__ __align__(16) float gi_buf[32*768];     // 96 KB
  __shared__ __align__(16) float out_buf[32*256];    // 32 KB
  if (t < 128){ hsbuf[0][t] = 0; }

  float hprev = 0.f;

  #pragma unroll 1
  for (int chunk = 0; chunk < 16; chunk++){
    int s0 = chunk * 32;
    int tlo = dir ? (LL - s0 - 32) : s0;    // staged t range [tlo, tlo+31]
    // stage 32 steps of gi: 6144 float4 over 512 threads; paced 4-in-flight
    {
      const float4* src = (const float4*)(GI + ((size_t)b*LL + tlo)*768);
      float4* dst = (float4*)gi_buf;
      #pragma unroll
      for (int rd = 0; rd < 3; rd++){
        float4 v0 = src[t + 512*(4*rd+0)];
        float4 v1 = src[t + 512*(4*rd+1)];
        float4 v2 = src[t + 512*(4*rd+2)];
        float4 v3 = src[t + 512*(4*rd+3)];
        dst[t + 512*(4*rd+0)] = v0;
        dst[t + 512*(4*rd+1)] = v1;
        dst[t + 512*(4*rd+2)] = v2;
        dst[t + 512*(4*rd+3)] = v3;
        __builtin_amdgcn_sched_barrier(0);
      }
    }
    __syncthreads();   // gi_buf ready; hs writes from prev step visible

    #pragma unroll 1
    for (int p = 0; p < 32; p++){
      int s = s0 + p;
      int tt = dir ? (LL-1-s) : s;
      int gidx = tt - tlo;                  // 0..31
      float ar0=0.f, ar1=0.f, az0=0.f, az1=0.f, an0=0.f, an1=0.f;
      // 4 paced sub-chunks: 4 uint4 h-words (16 u32) + 48 fdot2 each
      #pragma unroll
      for (int sc = 0; sc < 4; sc++){
        const uint4* hp = (const uint4*)(hsbuf[s & 1]) + ks*16 + sc*4;
        uint4 q0 = hp[0], q1 = hp[1], q2 = hp[2], q3 = hp[3];
        unsigned hv[16] = {q0.x,q0.y,q0.z,q0.w, q1.x,q1.y,q1.z,q1.w,
                           q2.x,q2.y,q2.z,q2.w, q3.x,q3.y,q3.z,q3.w};
        #pragma unroll
        for (int j = 0; j < 16; j += 2){
          int pp = sc*16 + j;
          ar0 = dot2_acc(w_r[pp  ], hv[j  ], ar0);
          az0 = dot2_acc(w_z[pp  ], hv[j  ], az0);
          an0 = dot2_acc(w_n[pp  ], hv[j  ], an0);
          ar1 = dot2_acc(w_r[pp+1], hv[j+1], ar1);
          az1 = dot2_acc(w_z[pp+1], hv[j+1], az1);
          an1 = dot2_acc(w_n[pp+1], hv[j+1], an1);
        }
        __builtin_amdgcn_sched_barrier(0);
      }
      float ar = ar0 + ar1, az = az0 + az1, an = an0 + an1;
      // combine the two k-halves: both lanes of the pair get the full sum
      ar += __shfl_xor(ar, 1, 64);
      az += __shfl_xor(az, 1, 64);
      an += __shfl_xor(an, 1, 64);
      const float* g = gi_buf + (size_t)gidx*768;
      float r  = sigmoid_fast(g[u      ] + ar + b_r);
      float z  = sigmoid_fast(g[u + 256] + az + b_z);
      float n  = tanh_fast  (g[u + 512] + r*(an + b_n));
      float hn = z*(hprev - n) + n;
      hprev = hn;
      if (ks == 0){
        out_buf[p*256 + u] = hn;
        ((unsigned short*)hsbuf[(s & 1) ^ 1])[u] =
            __builtin_bit_cast(unsigned short, (_Float16)hn);
      }
      __syncthreads();   // hs(write-buf) ready; separates reads from next writes
    }
    // flush outputs for this chunk (coalesced 256-wide per step); paced x4
    #pragma unroll
    for (int fr = 0; fr < 4; fr++){
      #pragma unroll
      for (int q = 0; q < 4; q++){
        int i = t + 512*(fr*4 + q);
        int p = i >> 8, uu = i & 255;
        int s = s0 + p;
        int tt = dir ? (LL-1-s) : s;
        out[((size_t)b*LL + tt)*(2*HH) + dir*HH + uu] = out_buf[i];
      }
      __builtin_amdgcn_sched_barrier(0);
    }
    __syncthreads();   // out_buf/gi_buf safe to reuse
  }
}

extern "C" void kernel_launch(void* const* d_in, const int* in_sizes, int n_in,
                              void* d_out, int out_size, void* d_ws, size_t ws_size,
                              hipStream_t stream)
{
  const float* P    = (const float*)d_in[0];
  const float* wq_w = (const float*)d_in[1];
  const float* wq_b = (const float*)d_in[2];
  const float* wp_w = (const float*)d_in[3];
  const float* wp_b = (const float*)d_in[4];
  const float* ws_w = (const float*)d_in[5];
  // d_in[6] = ws_b: softmax-invariant, unused
  const float* wg_w = (const float*)d_in[7];
  const float* wg_b = (const float*)d_in[8];
  const float* Wih_l= (const float*)d_in[9];
  const float* Whh_l= (const float*)d_in[10];
  const float* bih_l= (const float*)d_in[11];
  const float* bhh_l= (const float*)d_in[12];
  const float* Wih_r= (const float*)d_in[13];
  const float* Whh_r= (const float*)d_in[14];
  const float* bih_r= (const float*)d_in[15];
  const float* bhh_r= (const float*)d_in[16];

  float* ws  = (float*)d_ws;
  float* HQ  = ws;                    //  4,194,304
  float* PP  = ws + 4194304;          //  4,194,304
  float* S   = ws + 8388608;          //  8,388,608
  float* C   = ws + 16777216;         //  4,194,304
  float* CG  = ws + 20971520;         //  4,194,304
  float* GIR = ws + 25165824;         // 12,582,912
  float* GIL = ws;                    // 12,582,912 (aliases HQ/PP/S-front; dead by k6)
  float* out = (float*)d_out;

  k1_hq_pp  <<<dim3(128, 4),    256, 0, stream>>>(P, wq_w, wq_b, wp_w, wp_b, HQ, PP);
  k2_scores <<<dim3(16, 32),    256, 0, stream>>>(HQ, PP, ws_w, S);
  k3_softmax<<<4096,            256, 0, stream>>>(S);
  k4_context<<<dim3(2, 4, 32),  256, 0, stream>>>(S, P, C);
  k5_gate   <<<dim3(128, 2),    256, 0, stream>>>(P, C, wg_w, wg_b, CG);
  k6_gi     <<<dim3(128, 12),   256, 0, stream>>>(CG, Wih_l, bih_l, Wih_r, bih_r, GIL, GIR);
  k7_scan   <<<64,              512, 0, stream>>>(GIL, GIR, Whh_l, bhh_l, Whh_r, bhh_r, out);
}